// Round 3
// baseline (656.687 us; speedup 1.0000x reference)
//
#include <hip/hip_runtime.h>
#include <hip/hip_bf16.h>
#include <math.h>

#define NTOK 1024
#define DPROJ 1024
#define PSTRIDE 1376
#define HEADS 20003

typedef __attribute__((ext_vector_type(8))) short bf16x8;
typedef __attribute__((ext_vector_type(4))) float f32x4;

__device__ __forceinline__ short f2bf(float f) {
    unsigned u = __float_as_uint(f);
    u += 0x7fffu + ((u >> 16) & 1u);
    return (short)(u >> 16);
}

// async 16B/lane global->LDS (wave-uniform LDS base + lane*16)
__device__ __forceinline__ void gload_lds16(const short* g, short* l) {
    __builtin_amdgcn_global_load_lds(
        (const __attribute__((address_space(1))) unsigned*)(g),
        (__attribute__((address_space(3))) unsigned*)(l),
        16, 0, 0);
}

__global__ __launch_bounds__(256) void cvt_hidden(const float* __restrict__ h,
                                                  short* __restrict__ hb) {
    int i = (blockIdx.x * 256 + threadIdx.x) * 8;
    float4 a = *(const float4*)(h + i);
    float4 b = *(const float4*)(h + i + 4);
    bf16x8 o;
    o[0]=f2bf(a.x); o[1]=f2bf(a.y); o[2]=f2bf(a.z); o[3]=f2bf(a.w);
    o[4]=f2bf(b.x); o[5]=f2bf(b.y); o[6]=f2bf(b.z); o[7]=f2bf(b.w);
    *(bf16x8*)(hb + i) = o;
}

// p [DPROJ x d] row-major fp32 -> dst [d x DPROJ] bf16, LDS-tiled, coalesced both sides
__global__ __launch_bounds__(256) void transpose_p(const float* __restrict__ p,
                                                   short* __restrict__ dst, int d) {
    __shared__ float tile[64][65];
    int k0 = blockIdx.x * 64, j0 = blockIdx.y * 64;
    int tx = threadIdx.x & 63, ty = threadIdx.x >> 6;
    #pragma unroll
    for (int rr = 0; rr < 16; ++rr) {
        int k = k0 + ty * 16 + rr;
        int j = j0 + tx;
        if (j < d) tile[ty * 16 + rr][tx] = p[k * d + j];
    }
    __syncthreads();
    #pragma unroll
    for (int rr = 0; rr < 16; ++rr) {
        int j = j0 + ty * 16 + rr;
        if (j < d) dst[j * DPROJ + k0 + tx] = f2bf(tile[tx][ty * 16 + rr]);
    }
}

// proj = hidden @ p. 4 waves/block: wave w -> j-tile j0g + w*16. LDS-bounced coalesced stores.
// packed layout per cluster (unchanged from R2): chunk (tt*KS+ks) has lane (quad'*16+l16')
// = ((kk&31)>>3)*16 + (token&15) holding 8 bf16 of proj[token][kk = ks*32 + quad'*8 + (kk&7)].
__global__ __launch_bounds__(256) void proj_gemm(const short* __restrict__ hb,
                                                 const short* __restrict__ pTbc,
                                                 float* __restrict__ projf,
                                                 short* __restrict__ packedc,
                                                 int coloff, int KS, int d) {
    __shared__ float spackf[16][72];
    __shared__ short sp[1024];
    int tid = threadIdx.x;
    int w = tid >> 6, lane = tid & 63;
    int l16 = lane & 15, quad = lane >> 4;
    int tt = blockIdx.x;
    int t0 = tt * 16;
    int j0g = blockIdx.y * 64;
    int j0 = j0g + w * 16;

    if (j0 < d) {
        const short* aptr = hb + (t0 + l16) * DPROJ + quad * 8;
        const short* bptr = pTbc + (j0 + l16) * DPROJ + quad * 8;
        f32x4 acc = {0.f, 0.f, 0.f, 0.f};
        #pragma unroll 8
        for (int k0 = 0; k0 < DPROJ; k0 += 32) {
            bf16x8 a = *(const bf16x8*)(aptr + k0);
            bf16x8 b = *(const bf16x8*)(bptr + k0);
            acc = __builtin_amdgcn_mfma_f32_16x16x32_bf16(a, b, acc, 0, 0, 0);
        }
        int kk_local = w * 16 + l16;
        int ks_local = kk_local >> 5;
        #pragma unroll
        for (int r = 0; r < 4; ++r) {
            int tok = quad * 4 + r;
            spackf[tok][kk_local] = acc[r];
            sp[ks_local * 512 + ((kk_local & 31) >> 3) * 128 + tok * 8 + (kk_local & 7)] = f2bf(acc[r]);
        }
    }
    __syncthreads();

    int dcols = min(64, d - j0g);
    // projf: 16 rows x dcols, float4 per thread
    {
        int row = tid >> 4, cb = (tid & 15) * 4;
        if (cb < dcols) {
            float4 v = *(const float4*)&spackf[row][cb];
            *(float4*)&projf[(t0 + row) * PSTRIDE + coloff + j0g + cb] = v;
        }
    }
    // packed: 16*dcols shorts contiguous
    {
        int nshorts = 16 * dcols;
        if (tid * 4 < nshorts) {
            short* gdst = packedc + ((size_t)tt * KS + (j0g >> 5)) * 512 + tid * 4;
            *(short4*)gdst = *(const short4*)&sp[tid * 4];
        }
    }
}

// ---------------- head: single 32KB LDS buffer, global_load_lds staging, 4 indep acc chains
__global__ __launch_bounds__(256, 2) void lse_head(const float* __restrict__ w,
                                                   const float* __restrict__ bias,
                                                   const short* __restrict__ packed0,
                                                   float* __restrict__ sumrow, int V) {
    constexpr int KS = 32;
    __shared__ __align__(16) short sbuf[KS * 64 * 8];   // 32 KB
    __shared__ float bsum[NTOK / 16 * 16];              // 4 KB? -> bsum[1024]
    int tid = threadIdx.x;
    int wave = tid >> 6, lane = tid & 63;
    int quad = lane >> 4, l16 = lane & 15;
    int v0 = blockIdx.x * 64 + wave * 16;

    for (int i = tid; i < NTOK; i += 256) bsum[i] = 0.f;

    // resident A fragments (w fp32 -> bf16), 32 x 4 regs
    bf16x8 areg[KS];
    int va = v0 + l16;
    #pragma unroll
    for (int ks = 0; ks < KS; ++ks) {
        int k = ks * 32 + quad * 8;
        bf16x8 f;
        if (va < V) {
            const float* wp = w + (long)va * DPROJ + k;
            float4 x = *(const float4*)(wp);
            float4 y = *(const float4*)(wp + 4);
            f[0]=f2bf(x.x); f[1]=f2bf(x.y); f[2]=f2bf(x.z); f[3]=f2bf(x.w);
            f[4]=f2bf(y.x); f[5]=f2bf(y.y); f[6]=f2bf(y.z); f[7]=f2bf(y.w);
        } else {
            #pragma unroll
            for (int j = 0; j < 8; ++j) f[j] = 0;
        }
        areg[ks] = f;
    }
    float bb[4];
    #pragma unroll
    for (int r = 0; r < 4; ++r) {
        int vb = v0 + quad * 4 + r;
        bb[r] = (vb < V) ? bias[vb] : -1e30f;
    }

    for (int tt = 0; tt < 64; ++tt) {
        // stage tile tt: wave w copies bytes [w*8K, w*8K+8K)
        const short* g = packed0 + (size_t)tt * 16384 + (wave * 8) * 512 + lane * 8;
        short* lb = sbuf + (wave * 8) * 512;
        #pragma unroll
        for (int i = 0; i < 8; ++i)
            gload_lds16(g + i * 512, lb + i * 512);
        __syncthreads();   // drains vmcnt -> tile visible

        f32x4 a0 = {0,0,0,0}, a1 = {0,0,0,0}, a2 = {0,0,0,0}, a3 = {0,0,0,0};
        #pragma unroll
        for (int j = 0; j < 8; ++j) {
            bf16x8 b0 = *(const bf16x8*)(sbuf + ((j)      * 64 + lane) * 8);
            bf16x8 b1 = *(const bf16x8*)(sbuf + ((j + 8)  * 64 + lane) * 8);
            bf16x8 b2 = *(const bf16x8*)(sbuf + ((j + 16) * 64 + lane) * 8);
            bf16x8 b3 = *(const bf16x8*)(sbuf + ((j + 24) * 64 + lane) * 8);
            a0 = __builtin_amdgcn_mfma_f32_16x16x32_bf16(areg[j],      b0, a0, 0, 0, 0);
            a1 = __builtin_amdgcn_mfma_f32_16x16x32_bf16(areg[j + 8],  b1, a1, 0, 0, 0);
            a2 = __builtin_amdgcn_mfma_f32_16x16x32_bf16(areg[j + 16], b2, a2, 0, 0, 0);
            a3 = __builtin_amdgcn_mfma_f32_16x16x32_bf16(areg[j + 24], b3, a3, 0, 0, 0);
        }
        f32x4 acc = a0 + a1 + a2 + a3;
        float e = __expf(acc[0] + bb[0]) + __expf(acc[1] + bb[1]) +
                  __expf(acc[2] + bb[2]) + __expf(acc[3] + bb[3]);
        e += __shfl_xor(e, 16, 64);
        e += __shfl_xor(e, 32, 64);
        if (lane < 16) atomicAdd(&bsum[tt * 16 + lane], e);
        __syncthreads();   // before next stage overwrites sbuf
    }
    for (int i = tid; i < NTOK; i += 256)
        atomicAdd(&sumrow[i], bsum[i]);
}

// ---------------- tails: single-wave blocks, VT v-tiles resident, split chains for KS>=4
template <int KS, int VT>
__global__ __launch_bounds__(64) void lse_tail(const float* __restrict__ w,
                                               const float* __restrict__ bias,
                                               const short* __restrict__ packedc,
                                               float* __restrict__ sumrow,
                                               int V, int D) {
    __shared__ float blocksum[NTOK];
    int lane = threadIdx.x;
    int quad = lane >> 4, l16 = lane & 15;
    int v0 = blockIdx.x * (16 * VT);

    bf16x8 areg[VT][KS];
    float bb[VT][4];
    #pragma unroll
    for (int vt = 0; vt < VT; ++vt) {
        int va = v0 + vt * 16 + l16;
        #pragma unroll
        for (int ks = 0; ks < KS; ++ks) {
            int k = ks * 32 + quad * 8;
            bf16x8 f;
            if (va < V && k < D) {
                const float* wp = w + (long)va * D + k;
                float4 x = *(const float4*)(wp);
                float4 y = *(const float4*)(wp + 4);
                f[0]=f2bf(x.x); f[1]=f2bf(x.y); f[2]=f2bf(x.z); f[3]=f2bf(x.w);
                f[4]=f2bf(y.x); f[5]=f2bf(y.y); f[6]=f2bf(y.z); f[7]=f2bf(y.w);
            } else {
                #pragma unroll
                for (int j = 0; j < 8; ++j) f[j] = 0;
            }
            areg[vt][ks] = f;
        }
        #pragma unroll
        for (int r = 0; r < 4; ++r) {
            int vb = v0 + vt * 16 + quad * 4 + r;
            bb[vt][r] = (vb < V) ? bias[vb] : -1e30f;
        }
    }

    for (int tt = 0; tt < 64; ++tt) {
        const short* bp = packedc + ((size_t)tt * KS * 64 + lane) * 8;
        bf16x8 breg[KS];
        #pragma unroll
        for (int ks = 0; ks < KS; ++ks)
            breg[ks] = *(const bf16x8*)(bp + ks * 512);
        float e = 0.f;
        #pragma unroll
        for (int vt = 0; vt < VT; ++vt) {
            f32x4 acc;
            if constexpr (KS >= 4) {
                f32x4 x0 = {0,0,0,0}, x1 = {0,0,0,0};
                #pragma unroll
                for (int j = 0; j < KS / 2; ++j) {
                    x0 = __builtin_amdgcn_mfma_f32_16x16x32_bf16(areg[vt][j], breg[j], x0, 0, 0, 0);
                    x1 = __builtin_amdgcn_mfma_f32_16x16x32_bf16(areg[vt][KS/2 + j], breg[KS/2 + j], x1, 0, 0, 0);
                }
                acc = x0 + x1;
            } else {
                f32x4 x0 = {0,0,0,0};
                #pragma unroll
                for (int j = 0; j < KS; ++j)
                    x0 = __builtin_amdgcn_mfma_f32_16x16x32_bf16(areg[vt][j], breg[j], x0, 0, 0, 0);
                acc = x0;
            }
            e += __expf(acc[0] + bb[vt][0]) + __expf(acc[1] + bb[vt][1]) +
                 __expf(acc[2] + bb[vt][2]) + __expf(acc[3] + bb[vt][3]);
        }
        e += __shfl_xor(e, 16, 64);
        e += __shfl_xor(e, 32, 64);
        if (lane < 16) blocksum[tt * 16 + lane] = e;
    }
    for (int i = lane; i < NTOK; i += 64)
        atomicAdd(&sumrow[i], blocksum[i]);
}

__global__ __launch_bounds__(256) void finalize(const int* __restrict__ target,
                                                const float* __restrict__ projf,
                                                const float* __restrict__ sums,
                                                const float* __restrict__ w0, const float* __restrict__ b0,
                                                const float* __restrict__ w1, const float* __restrict__ b1,
                                                const float* __restrict__ w2, const float* __restrict__ b2,
                                                const float* __restrict__ w3, const float* __restrict__ b3,
                                                float* __restrict__ out) {
    int wave = threadIdx.x >> 6, lane = threadIdx.x & 63;
    int row = blockIdx.x * 4 + wave;
    int t = target[row];
    int c = (t < 20000) ? 0 : (t < 40000) ? 1 : (t < 200000) ? 2 : 3;
    int col0 = (c == 0) ? t : (HEADS - c);
    const float* pr = projf + row * PSTRIDE;

    float s = 0.f;
    for (int k = lane; k < DPROJ; k += 64) s += pr[k] * w0[col0 * DPROJ + k];
    #pragma unroll
    for (int off = 32; off; off >>= 1) s += __shfl_xor(s, off, 64);
    float hl = s + b0[col0];
    float lse0 = __logf(sums[row]);

    float res;
    if (c == 0) {
        res = lse0 - hl;
    } else {
        const float* wc; const float* bc; int d, coloff, l;
        if (c == 1)      { wc = w1; bc = b1; d = 256; coloff = 1024; l = 20000; }
        else if (c == 2) { wc = w2; bc = b2; d = 64;  coloff = 1280; l = 40000; }
        else             { wc = w3; bc = b3; d = 16;  coloff = 1344; l = 200000; }
        int tc = t - l;
        float s2 = 0.f;
        for (int k = lane; k < d; k += 64) s2 += pr[coloff + k] * wc[tc * d + k];
        #pragma unroll
        for (int off = 32; off; off >>= 1) s2 += __shfl_xor(s2, off, 64);
        float tl = s2 + bc[tc];
        float lsec = __logf(sums[c * NTOK + row]);
        res = lse0 - hl + lsec - tl;
    }
    if (lane == 0) out[row] = res;
}

// workspace layout (bytes)
#define HB_OFF    0ull
#define PTB_OFF   (HB_OFF + 1024ull*1024*2)
#define PROJF_OFF (PTB_OFF + 1360ull*1024*2)
#define PACK_OFF  (PROJF_OFF + 1024ull*1376*4)
#define SUM_OFF   (PACK_OFF + 1409024ull*2)

extern "C" void kernel_launch(void* const* d_in, const int* in_sizes, int n_in,
                              void* d_out, int out_size, void* d_ws, size_t ws_size,
                              hipStream_t stream) {
    const float* hidden = (const float*)d_in[0];
    const int*   target = (const int*)d_in[1];
    const float* w0 = (const float*)d_in[2];
    const float* b0 = (const float*)d_in[3];
    const float* p0 = (const float*)d_in[4];
    const float* w1 = (const float*)d_in[5];
    const float* b1 = (const float*)d_in[6];
    const float* p1 = (const float*)d_in[7];
    const float* w2 = (const float*)d_in[8];
    const float* b2 = (const float*)d_in[9];
    const float* p2 = (const float*)d_in[10];
    const float* w3 = (const float*)d_in[11];
    const float* b3 = (const float*)d_in[12];
    const float* p3 = (const float*)d_in[13];

    char* ws = (char*)d_ws;
    short* hb    = (short*)(ws + HB_OFF);
    short* pTb   = (short*)(ws + PTB_OFF);
    float* projf = (float*)(ws + PROJF_OFF);
    short* pk    = (short*)(ws + PACK_OFF);
    float* sums  = (float*)(ws + SUM_OFF);
    short* pk0 = pk;
    short* pk1 = pk0 + 64 * 32 * 64 * 8;
    short* pk2 = pk1 + 64 * 8 * 64 * 8;
    short* pk3 = pk2 + 64 * 2 * 64 * 8;

    cvt_hidden<<<512, 256, 0, stream>>>(hidden, hb);
    transpose_p<<<dim3(16, 16), 256, 0, stream>>>(p0, pTb + 0, 1024);
    transpose_p<<<dim3(16, 4),  256, 0, stream>>>(p1, pTb + 1024 * 1024, 256);
    transpose_p<<<dim3(16, 1),  256, 0, stream>>>(p2, pTb + 1280 * 1024, 64);
    transpose_p<<<dim3(16, 1),  256, 0, stream>>>(p3, pTb + 1344 * 1024, 16);
    hipMemsetAsync(ws + PACK_OFF, 0, 1409024 * 2, stream);
    hipMemsetAsync(ws + SUM_OFF, 0, 4 * NTOK * sizeof(float), stream);

    proj_gemm<<<dim3(64, 16), 256, 0, stream>>>(hb, pTb + 0,           projf, pk0, 0,    32, 1024);
    proj_gemm<<<dim3(64, 4),  256, 0, stream>>>(hb, pTb + 1024 * 1024, projf, pk1, 1024, 8,  256);
    proj_gemm<<<dim3(64, 1),  256, 0, stream>>>(hb, pTb + 1280 * 1024, projf, pk2, 1280, 2,  64);
    proj_gemm<<<dim3(64, 1),  256, 0, stream>>>(hb, pTb + 1344 * 1024, projf, pk3, 1344, 1,  16);

    lse_head<<<313, 256, 0, stream>>>(w0, b0, pk0, sums + 0 * NTOK, HEADS);
    lse_tail<8, 2><<<625, 64, 0, stream>>>(w1, b1, pk1, sums + 1 * NTOK, 20000, 256);
    lse_tail<2, 4><<<2500, 64, 0, stream>>>(w2, b2, pk2, sums + 2 * NTOK, 160000, 64);
    lse_tail<1, 4><<<1059, 64, 0, stream>>>(w3, b3, pk3, sums + 3 * NTOK, 67735, 16);

    finalize<<<256, 256, 0, stream>>>(target, projf, sums,
                                      w0, b0, w1, b1, w2, b2, w3, b3, (float*)d_out);
}

// Round 4
// 466.686 us; speedup vs baseline: 1.4071x; 1.4071x over previous
//
#include <hip/hip_runtime.h>
#include <hip/hip_bf16.h>
#include <math.h>

#define NTOK 1024
#define DPROJ 1024
#define PSTRIDE 1376
#define HEADS 20003

typedef __attribute__((ext_vector_type(8))) short bf16x8;
typedef __attribute__((ext_vector_type(4))) float f32x4;

__device__ __forceinline__ short f2bf(float f) {
    unsigned u = __float_as_uint(f);
    u += 0x7fffu + ((u >> 16) & 1u);
    return (short)(u >> 16);
}

// ================= prep: hidden->A-frags, p->B-frags (all coalesced out) ========
// hbP chunk (tt*32+ks): lane l holds hidden[tt*16+(l&15)][ks*32+(l>>4)*8 + e], e=0..7
// pTbP_c chunk (jt*32+ks): lane l holds pT[jt*16+(l&15)][ks*32+(l>>4)*8 + e]
__global__ __launch_bounds__(256) void prep(const float* __restrict__ hidden,
                                            const float* __restrict__ p0,
                                            const float* __restrict__ p1,
                                            const float* __restrict__ p2,
                                            const float* __restrict__ p3,
                                            short* __restrict__ hbP,
                                            short* __restrict__ pTbP0,
                                            short* __restrict__ pTbP1,
                                            short* __restrict__ pTbP2,
                                            short* __restrict__ pTbP3) {
    __shared__ float tile[64][65];
    int bid = blockIdx.x, tid = threadIdx.x;
    if (bid < 64) {
        int tt = bid;
        #pragma unroll
        for (int q = 0; q < 8; ++q) {
            int fi = q * 256 + tid;           // frag id = ks*64 + lane
            int l = fi & 63;
            int row = tt * 16 + (l & 15);
            int kb = (fi >> 6) * 32 + (l >> 4) * 8;
            const float* hp = hidden + row * 1024 + kb;
            float4 x = *(const float4*)hp;
            float4 y = *(const float4*)(hp + 4);
            bf16x8 o;
            o[0]=f2bf(x.x); o[1]=f2bf(x.y); o[2]=f2bf(x.z); o[3]=f2bf(x.w);
            o[4]=f2bf(y.x); o[5]=f2bf(y.y); o[6]=f2bf(y.z); o[7]=f2bf(y.w);
            *(bf16x8*)(hbP + (size_t)tt * 16384 + fi * 8) = o;
        }
        return;
    }
    int lb = bid - 64;
    const float* p; short* dst; int d, kt, jb;
    if (lb < 256)      { p = p0; dst = pTbP0; d = 1024; kt = lb >> 4; jb = lb & 15; }
    else if (lb < 320) { lb -= 256; p = p1; dst = pTbP1; d = 256; kt = lb >> 2; jb = lb & 3; }
    else if (lb < 336) { lb -= 320; p = p2; dst = pTbP2; d = 64;  kt = lb; jb = 0; }
    else               { lb -= 336; p = p3; dst = pTbP3; d = 16;  kt = lb; jb = 0; }
    int k0 = kt * 64, j0 = jb * 64;
    int tx = tid & 63, ty = tid >> 6;
    #pragma unroll
    for (int rr = 0; rr < 16; ++rr) {
        int k = k0 + ty * 16 + rr;
        int j = j0 + tx;
        if (j < d) tile[ty * 16 + rr][tx] = p[k * d + j];
    }
    __syncthreads();
    int ch = tid >> 5;                 // 8 chunks: jtl=ch>>1, ksl=ch&1
    int jtl = ch >> 1, ksl = ch & 1;
    int jt = jb * 4 + jtl;
    if (jt * 16 < d) {
        #pragma unroll
        for (int li = 0; li < 2; ++li) {
            int l = (tid & 31) + li * 32;
            int jl = jtl * 16 + (l & 15);
            int kl = ksl * 32 + (l >> 4) * 8;
            bf16x8 o;
            #pragma unroll
            for (int e = 0; e < 8; ++e) o[e] = f2bf(tile[kl + e][jl]);
            *(bf16x8*)(dst + ((size_t)jt * 32 + kt * 2 + ksl) * 512 + l * 8) = o;
        }
    }
}

// ================= proj: one kernel, all clusters. Coalesced frag loads. ==========
__global__ __launch_bounds__(256) void proj(const short* __restrict__ hbP,
                                            const short* __restrict__ pTbP0,
                                            const short* __restrict__ pTbP1,
                                            const short* __restrict__ pTbP2,
                                            const short* __restrict__ pTbP3,
                                            float* __restrict__ projf,
                                            short* __restrict__ pk0,
                                            short* __restrict__ pk1,
                                            short* __restrict__ pk2,
                                            short* __restrict__ pk3) {
    __shared__ float spackf[16][72];
    __shared__ short sp[1024];
    int tt = blockIdx.x, jbG = blockIdx.y, tid = threadIdx.x;
    const short* pB; short* pkc; int d, KSp, coloff, jb;
    if (jbG < 16)      { pB = pTbP0; pkc = pk0; d = 1024; KSp = 32; coloff = 0;    jb = jbG; }
    else if (jbG < 20) { pB = pTbP1; pkc = pk1; d = 256;  KSp = 8;  coloff = 1024; jb = jbG - 16; }
    else if (jbG == 20){ pB = pTbP2; pkc = pk2; d = 64;   KSp = 2;  coloff = 1280; jb = 0; }
    else               { pB = pTbP3; pkc = pk3; d = 16;   KSp = 1;  coloff = 1344; jb = 0; }
    int w = tid >> 6, lane = tid & 63;
    int l16 = lane & 15, quad = lane >> 4;
    int jt = jb * 4 + w;
    if (jt * 16 < d) {
        const short* ap = hbP + ((size_t)tt * 32) * 512 + lane * 8;
        const short* bp = pB  + ((size_t)jt * 32) * 512 + lane * 8;
        f32x4 x0 = {0,0,0,0}, x1 = {0,0,0,0};
        #pragma unroll
        for (int ks = 0; ks < 16; ++ks) {
            bf16x8 a0 = *(const bf16x8*)(ap + ks * 512);
            bf16x8 b0 = *(const bf16x8*)(bp + ks * 512);
            bf16x8 a1 = *(const bf16x8*)(ap + (ks + 16) * 512);
            bf16x8 b1 = *(const bf16x8*)(bp + (ks + 16) * 512);
            x0 = __builtin_amdgcn_mfma_f32_16x16x32_bf16(a0, b0, x0, 0, 0, 0);
            x1 = __builtin_amdgcn_mfma_f32_16x16x32_bf16(a1, b1, x1, 0, 0, 0);
        }
        f32x4 acc = x0 + x1;
        int kk = w * 16 + l16;              // col within the 64-col block
        #pragma unroll
        for (int r = 0; r < 4; ++r) {
            int tok = quad * 4 + r;
            spackf[tok][kk] = acc[r];
            sp[(kk >> 5) * 512 + ((kk & 31) >> 3) * 128 + tok * 8 + (kk & 7)] = f2bf(acc[r]);
        }
    }
    __syncthreads();
    int j0g = jb * 64;
    int dcols = min(64, d - j0g);
    {
        int row = tid >> 4, cb = (tid & 15) * 4;
        if (cb < dcols) {
            float4 v = *(const float4*)&spackf[row][cb];
            *(float4*)&projf[(tt * 16 + row) * PSTRIDE + coloff + j0g + cb] = v;
        }
    }
    {
        int nshorts = 16 * dcols;
        if (tid * 4 < nshorts) {
            short* gdst = pkc + ((size_t)tt * KSp + (j0g >> 5)) * 512 + tid * 4;
            *(short4*)gdst = *(const short4*)&sp[tid * 4];
        }
    }
}

// ================= lse: one kernel, all clusters, token-split, global-direct B ====
template <int KS, int VT, int TS>
__device__ __forceinline__ void lse_cluster(const float* __restrict__ w,
                                            const float* __restrict__ bias,
                                            const short* __restrict__ packedc,
                                            float* __restrict__ sumrowc,
                                            int V, int D, int bidLocal,
                                            float* bsum) {
    constexpr int TTN = 64 / TS;
    int tid = threadIdx.x;
    int rb = bidLocal / TS, th = bidLocal % TS;
    int wave = tid >> 6, lane = tid & 63;
    int quad = lane >> 4, l16 = lane & 15;
    int v0 = rb * (64 * VT) + wave * (16 * VT);

    for (int i = tid; i < TTN * 16; i += 256) bsum[i] = 0.f;
    __syncthreads();

    bf16x8 areg[VT][KS];
    float bb[VT][4];
    #pragma unroll
    for (int vt = 0; vt < VT; ++vt) {
        int va = v0 + vt * 16 + l16;
        #pragma unroll
        for (int ks = 0; ks < KS; ++ks) {
            int k = ks * 32 + quad * 8;
            bf16x8 f;
            if (va < V && k < D) {
                const float* wp = w + (long)va * D + k;
                float4 x = *(const float4*)(wp);
                float4 y = *(const float4*)(wp + 4);
                f[0]=f2bf(x.x); f[1]=f2bf(x.y); f[2]=f2bf(x.z); f[3]=f2bf(x.w);
                f[4]=f2bf(y.x); f[5]=f2bf(y.y); f[6]=f2bf(y.z); f[7]=f2bf(y.w);
            } else {
                #pragma unroll
                for (int j = 0; j < 8; ++j) f[j] = 0;
            }
            areg[vt][ks] = f;
        }
        #pragma unroll
        for (int r = 0; r < 4; ++r) {
            int vb = v0 + vt * 16 + quad * 4 + r;
            bb[vt][r] = (vb < V) ? bias[vb] : -1e30f;
        }
    }

    for (int t = 0; t < TTN; ++t) {
        int tt = th * TTN + t;
        const short* bp = packedc + ((size_t)tt * KS) * 512 + lane * 8;
        float e = 0.f;
        if constexpr (KS == 32) {
            f32x4 a0 = {0,0,0,0}, a1 = a0, a2 = a0, a3 = a0;
            #pragma unroll
            for (int j = 0; j < 8; ++j) {
                bf16x8 b0 = *(const bf16x8*)(bp + (j)      * 512);
                bf16x8 b1 = *(const bf16x8*)(bp + (j + 8)  * 512);
                bf16x8 b2 = *(const bf16x8*)(bp + (j + 16) * 512);
                bf16x8 b3 = *(const bf16x8*)(bp + (j + 24) * 512);
                a0 = __builtin_amdgcn_mfma_f32_16x16x32_bf16(areg[0][j],      b0, a0, 0, 0, 0);
                a1 = __builtin_amdgcn_mfma_f32_16x16x32_bf16(areg[0][j + 8],  b1, a1, 0, 0, 0);
                a2 = __builtin_amdgcn_mfma_f32_16x16x32_bf16(areg[0][j + 16], b2, a2, 0, 0, 0);
                a3 = __builtin_amdgcn_mfma_f32_16x16x32_bf16(areg[0][j + 24], b3, a3, 0, 0, 0);
            }
            f32x4 acc = a0 + a1 + a2 + a3;
            e = __expf(acc[0] + bb[0][0]) + __expf(acc[1] + bb[0][1]) +
                __expf(acc[2] + bb[0][2]) + __expf(acc[3] + bb[0][3]);
        } else {
            bf16x8 breg[KS];
            #pragma unroll
            for (int ks = 0; ks < KS; ++ks)
                breg[ks] = *(const bf16x8*)(bp + ks * 512);
            #pragma unroll
            for (int vt = 0; vt < VT; ++vt) {
                f32x4 acc = {0,0,0,0};
                #pragma unroll
                for (int ks = 0; ks < KS; ++ks)
                    acc = __builtin_amdgcn_mfma_f32_16x16x32_bf16(areg[vt][ks], breg[ks], acc, 0, 0, 0);
                e += __expf(acc[0] + bb[vt][0]) + __expf(acc[1] + bb[vt][1]) +
                     __expf(acc[2] + bb[vt][2]) + __expf(acc[3] + bb[vt][3]);
            }
        }
        e += __shfl_xor(e, 16, 64);
        e += __shfl_xor(e, 32, 64);
        if (lane < 16) atomicAdd(&bsum[t * 16 + lane], e);
    }
    __syncthreads();
    int tokBase = th * TTN * 16;
    for (int i = tid; i < TTN * 16; i += 256)
        atomicAdd(&sumrowc[tokBase + i], bsum[i]);
}

#define NB0 626
#define NB1 628
#define NB2 1250
#define NB3 530

__global__ __launch_bounds__(256) void lse_all(const float* __restrict__ w0, const float* __restrict__ b0,
                                               const float* __restrict__ w1, const float* __restrict__ b1,
                                               const float* __restrict__ w2, const float* __restrict__ b2,
                                               const float* __restrict__ w3, const float* __restrict__ b3,
                                               const short* __restrict__ pk0, const short* __restrict__ pk1,
                                               const short* __restrict__ pk2, const short* __restrict__ pk3,
                                               float* __restrict__ sums) {
    __shared__ float bsum[512];
    int bid = blockIdx.x;
    if (bid < NB0) {
        lse_cluster<32, 1, 2>(w0, b0, pk0, sums,            HEADS,  1024, bid, bsum);
    } else if (bid < NB0 + NB1) {
        lse_cluster<8, 2, 4>(w1, b1, pk1, sums + NTOK,      20000,  256,  bid - NB0, bsum);
    } else if (bid < NB0 + NB1 + NB2) {
        lse_cluster<2, 4, 2>(w2, b2, pk2, sums + 2 * NTOK,  160000, 64,   bid - NB0 - NB1, bsum);
    } else {
        lse_cluster<1, 4, 2>(w3, b3, pk3, sums + 3 * NTOK,  67735,  16,   bid - NB0 - NB1 - NB2, bsum);
    }
}

// ================= finalize (unchanged) ==========================================
__global__ __launch_bounds__(256) void finalize(const int* __restrict__ target,
                                                const float* __restrict__ projf,
                                                const float* __restrict__ sums,
                                                const float* __restrict__ w0, const float* __restrict__ b0,
                                                const float* __restrict__ w1, const float* __restrict__ b1,
                                                const float* __restrict__ w2, const float* __restrict__ b2,
                                                const float* __restrict__ w3, const float* __restrict__ b3,
                                                float* __restrict__ out) {
    int wave = threadIdx.x >> 6, lane = threadIdx.x & 63;
    int row = blockIdx.x * 4 + wave;
    int t = target[row];
    int c = (t < 20000) ? 0 : (t < 40000) ? 1 : (t < 200000) ? 2 : 3;
    int col0 = (c == 0) ? t : (HEADS - c);
    const float* pr = projf + row * PSTRIDE;

    float s = 0.f;
    for (int k = lane; k < DPROJ; k += 64) s += pr[k] * w0[col0 * DPROJ + k];
    #pragma unroll
    for (int off = 32; off; off >>= 1) s += __shfl_xor(s, off, 64);
    float hl = s + b0[col0];
    float lse0 = __logf(sums[row]);

    float res;
    if (c == 0) {
        res = lse0 - hl;
    } else {
        const float* wc; const float* bc; int d, coloff, l;
        if (c == 1)      { wc = w1; bc = b1; d = 256; coloff = 1024; l = 20000; }
        else if (c == 2) { wc = w2; bc = b2; d = 64;  coloff = 1280; l = 40000; }
        else             { wc = w3; bc = b3; d = 16;  coloff = 1344; l = 200000; }
        int tc = t - l;
        float s2 = 0.f;
        for (int k = lane; k < d; k += 64) s2 += pr[coloff + k] * wc[tc * d + k];
        #pragma unroll
        for (int off = 32; off; off >>= 1) s2 += __shfl_xor(s2, off, 64);
        float tl = s2 + bc[tc];
        float lsec = __logf(sums[c * NTOK + row]);
        res = lse0 - hl + lsec - tl;
    }
    if (lane == 0) out[row] = res;
}

// ================= workspace layout (shorts unless noted) ========================
// hbP    : 1,048,576            @ 0
// pTbP0  : 1,048,576            @ 1,048,576
// pTbP1  :   262,144            @ 2,097,152
// pTbP2  :    65,536            @ 2,359,296
// pTbP3  :    16,384            @ 2,424,832
// projf  : 1,409,024 floats     @ byte 4,882,432
// pk0..3 : 1,048,576/262,144/65,536/32,768 shorts @ byte 10,518,528
// sums   : 4096 floats, OVERLAPS pTbP0 (dead after proj)

extern "C" void kernel_launch(void* const* d_in, const int* in_sizes, int n_in,
                              void* d_out, int out_size, void* d_ws, size_t ws_size,
                              hipStream_t stream) {
    const float* hidden = (const float*)d_in[0];
    const int*   target = (const int*)d_in[1];
    const float* w0 = (const float*)d_in[2];
    const float* b0 = (const float*)d_in[3];
    const float* p0 = (const float*)d_in[4];
    const float* w1 = (const float*)d_in[5];
    const float* b1 = (const float*)d_in[6];
    const float* p1 = (const float*)d_in[7];
    const float* w2 = (const float*)d_in[8];
    const float* b2 = (const float*)d_in[9];
    const float* p2 = (const float*)d_in[10];
    const float* w3 = (const float*)d_in[11];
    const float* b3 = (const float*)d_in[12];
    const float* p3 = (const float*)d_in[13];

    short* base = (short*)d_ws;
    short* hbP   = base;
    short* pTbP0 = base + 1048576;
    short* pTbP1 = base + 2097152;
    short* pTbP2 = base + 2359296;
    short* pTbP3 = base + 2424832;
    float* projf = (float*)((char*)d_ws + 4882432);
    short* pk0   = (short*)((char*)d_ws + 10518528);
    short* pk1   = pk0 + 1048576;
    short* pk2   = pk1 + 262144;
    short* pk3   = pk2 + 65536;
    float* sums  = (float*)pTbP0;          // reuse: pTbP0 dead after proj

    prep<<<416, 256, 0, stream>>>(hidden, p0, p1, p2, p3, hbP, pTbP0, pTbP1, pTbP2, pTbP3);
    hipMemsetAsync(pk3, 0, 32768 * 2, stream);   // c3 k-pad zeros
    proj<<<dim3(64, 22), 256, 0, stream>>>(hbP, pTbP0, pTbP1, pTbP2, pTbP3,
                                           projf, pk0, pk1, pk2, pk3);
    hipMemsetAsync(sums, 0, 4 * NTOK * sizeof(float), stream);   // after proj: safe overlap
    lse_all<<<NB0 + NB1 + NB2 + NB3, 256, 0, stream>>>(w0, b0, w1, b1, w2, b2, w3, b3,
                                                       pk0, pk1, pk2, pk3, sums);
    finalize<<<256, 256, 0, stream>>>(target, projf, sums,
                                      w0, b0, w1, b1, w2, b2, w3, b3, (float*)d_out);
}

// Round 5
// 371.444 us; speedup vs baseline: 1.7679x; 1.2564x over previous
//
#include <hip/hip_runtime.h>
#include <hip/hip_bf16.h>
#include <math.h>

#define NTOK 1024
#define DPROJ 1024
#define PSTRIDE 1376
#define HEADS 20003

typedef __attribute__((ext_vector_type(8))) short bf16x8;
typedef __attribute__((ext_vector_type(4))) float f32x4;
typedef long long i64;

__device__ __forceinline__ short f2bf(float f) {
    unsigned u = __float_as_uint(f);
    u += 0x7fffu + ((u >> 16) & 1u);
    return (short)(u >> 16);
}

// pack 4 floats -> 4 OCP e4m3 bytes
__device__ __forceinline__ unsigned pk4fp8(float a, float b, float c, float d) {
    unsigned v = __builtin_amdgcn_cvt_pk_fp8_f32(a, b, 0, false);
    v = __builtin_amdgcn_cvt_pk_fp8_f32(c, d, v, true);
    return v;
}
__device__ __forceinline__ unsigned char fp8_1(float a) {
    return (unsigned char)(__builtin_amdgcn_cvt_pk_fp8_f32(a, a, 0, false) & 0xff);
}

// ================= prep: hidden->A-frags, p->B-frags (bf16, for proj) ===========
__global__ __launch_bounds__(256) void prep(const float* __restrict__ hidden,
                                            const float* __restrict__ p0,
                                            const float* __restrict__ p1,
                                            const float* __restrict__ p2,
                                            const float* __restrict__ p3,
                                            short* __restrict__ hbP,
                                            short* __restrict__ pTbP0,
                                            short* __restrict__ pTbP1,
                                            short* __restrict__ pTbP2,
                                            short* __restrict__ pTbP3) {
    __shared__ float tile[64][65];
    int bid = blockIdx.x, tid = threadIdx.x;
    if (bid < 64) {
        int tt = bid;
        #pragma unroll
        for (int q = 0; q < 8; ++q) {
            int fi = q * 256 + tid;
            int l = fi & 63;
            int row = tt * 16 + (l & 15);
            int kb = (fi >> 6) * 32 + (l >> 4) * 8;
            const float* hp = hidden + row * 1024 + kb;
            float4 x = *(const float4*)hp;
            float4 y = *(const float4*)(hp + 4);
            bf16x8 o;
            o[0]=f2bf(x.x); o[1]=f2bf(x.y); o[2]=f2bf(x.z); o[3]=f2bf(x.w);
            o[4]=f2bf(y.x); o[5]=f2bf(y.y); o[6]=f2bf(y.z); o[7]=f2bf(y.w);
            *(bf16x8*)(hbP + (size_t)tt * 16384 + fi * 8) = o;
        }
        return;
    }
    int lb = bid - 64;
    const float* p; short* dst; int d, kt, jb;
    if (lb < 256)      { p = p0; dst = pTbP0; d = 1024; kt = lb >> 4; jb = lb & 15; }
    else if (lb < 320) { lb -= 256; p = p1; dst = pTbP1; d = 256; kt = lb >> 2; jb = lb & 3; }
    else if (lb < 336) { lb -= 320; p = p2; dst = pTbP2; d = 64;  kt = lb; jb = 0; }
    else               { lb -= 336; p = p3; dst = pTbP3; d = 16;  kt = lb; jb = 0; }
    int k0 = kt * 64, j0 = jb * 64;
    int tx = tid & 63, ty = tid >> 6;
    #pragma unroll
    for (int rr = 0; rr < 16; ++rr) {
        int k = k0 + ty * 16 + rr;
        int j = j0 + tx;
        if (j < d) tile[ty * 16 + rr][tx] = p[k * d + j];
    }
    __syncthreads();
    int ch = tid >> 5;
    int jtl = ch >> 1, ksl = ch & 1;
    int jt = jb * 4 + jtl;
    if (jt * 16 < d) {
        #pragma unroll
        for (int li = 0; li < 2; ++li) {
            int l = (tid & 31) + li * 32;
            int jl = jtl * 16 + (l & 15);
            int kl = ksl * 32 + (l >> 4) * 8;
            bf16x8 o;
            #pragma unroll
            for (int e = 0; e < 8; ++e) o[e] = f2bf(tile[kl + e][jl]);
            *(bf16x8*)(dst + ((size_t)jt * 32 + kt * 2 + ksl) * 512 + l * 8) = o;
        }
    }
}

// ================= proj: bf16 MFMA, writes fp32 projf + fp8 packed frags ========
__global__ __launch_bounds__(256) void proj(const short* __restrict__ hbP,
                                            const short* __restrict__ pTbP0,
                                            const short* __restrict__ pTbP1,
                                            const short* __restrict__ pTbP2,
                                            const short* __restrict__ pTbP3,
                                            float* __restrict__ projf,
                                            unsigned char* __restrict__ pk0,
                                            unsigned char* __restrict__ pk1,
                                            unsigned char* __restrict__ pk2,
                                            unsigned char* __restrict__ pk3) {
    __shared__ float spackf[16][72];
    __shared__ unsigned char sp8[1024];
    int tt = blockIdx.x, jbG = blockIdx.y, tid = threadIdx.x;
    const short* pB; unsigned char* pkc; int d, KSp, coloff, jb;
    if (jbG < 16)      { pB = pTbP0; pkc = pk0; d = 1024; KSp = 32; coloff = 0;    jb = jbG; }
    else if (jbG < 20) { pB = pTbP1; pkc = pk1; d = 256;  KSp = 8;  coloff = 1024; jb = jbG - 16; }
    else if (jbG == 20){ pB = pTbP2; pkc = pk2; d = 64;   KSp = 2;  coloff = 1280; jb = 0; }
    else               { pB = pTbP3; pkc = pk3; d = 16;   KSp = 1;  coloff = 1344; jb = 0; }
    int w = tid >> 6, lane = tid & 63;
    int l16 = lane & 15, quad = lane >> 4;
    int jt = jb * 4 + w;
    if (jt * 16 < d) {
        const short* ap = hbP + ((size_t)tt * 32) * 512 + lane * 8;
        const short* bp = pB  + ((size_t)jt * 32) * 512 + lane * 8;
        f32x4 x0 = {0,0,0,0}, x1 = {0,0,0,0};
        #pragma unroll
        for (int ks = 0; ks < 16; ++ks) {
            bf16x8 a0 = *(const bf16x8*)(ap + ks * 512);
            bf16x8 b0 = *(const bf16x8*)(bp + ks * 512);
            bf16x8 a1 = *(const bf16x8*)(ap + (ks + 16) * 512);
            bf16x8 b1 = *(const bf16x8*)(bp + (ks + 16) * 512);
            x0 = __builtin_amdgcn_mfma_f32_16x16x32_bf16(a0, b0, x0, 0, 0, 0);
            x1 = __builtin_amdgcn_mfma_f32_16x16x32_bf16(a1, b1, x1, 0, 0, 0);
        }
        f32x4 acc = x0 + x1;
        int kk = w * 16 + l16;
        #pragma unroll
        for (int r = 0; r < 4; ++r) {
            int tok = quad * 4 + r;
            spackf[tok][kk] = acc[r];
            sp8[(kk >> 5) * 512 + ((kk & 31) >> 3) * 128 + tok * 8 + (kk & 7)] = fp8_1(acc[r]);
        }
    }
    __syncthreads();
    int j0g = jb * 64;
    int dcols = min(64, d - j0g);
    {
        int row = tid >> 4, cb = (tid & 15) * 4;
        if (cb < dcols) {
            float4 v = *(const float4*)&spackf[row][cb];
            *(float4*)&projf[(tt * 16 + row) * PSTRIDE + coloff + j0g + cb] = v;
        }
    }
    {
        int nbytes = 16 * dcols;
        if (tid * 4 < nbytes) {
            unsigned char* gdst = pkc + ((size_t)tt * KSp + (j0g >> 5)) * 512;
            *(unsigned*)(gdst + tid * 4) = *(const unsigned*)(sp8 + tid * 4);
        }
    }
}

// ================= lse: fp8 MFMA, A (w rows) resident, no token split ===========
template <int KS, int VT>
__device__ __forceinline__ void lse_cluster(const float* __restrict__ w,
                                            const float* __restrict__ bias,
                                            const unsigned char* __restrict__ pkc,
                                            float* __restrict__ sumrowc,
                                            int V, int D, int bidLocal,
                                            float* bsum) {
    int tid = threadIdx.x;
    int wave = tid >> 6, lane = tid & 63;
    int quad = lane >> 4, l16 = lane & 15;
    int v0 = bidLocal * (64 * VT) + wave * (16 * VT);

    for (int i = tid; i < NTOK; i += 256) bsum[i] = 0.f;
    __syncthreads();

    // resident A fragments: w fp32 -> fp8 e4m3, 8 contiguous k per lane
    i64 areg[VT][KS];
    float bb[VT][4];
    #pragma unroll
    for (int vt = 0; vt < VT; ++vt) {
        int va = v0 + vt * 16 + l16;
        #pragma unroll
        for (int ks = 0; ks < KS; ++ks) {
            int k = ks * 32 + quad * 8;
            if (va < V && k < D) {
                const float* wp = w + (long)va * D + k;
                float4 x = *(const float4*)(wp);
                float4 y = *(const float4*)(wp + 4);
                unsigned lo = pk4fp8(x.x, x.y, x.z, x.w);
                unsigned hi = pk4fp8(y.x, y.y, y.z, y.w);
                areg[vt][ks] = (i64)(((unsigned long long)hi << 32) | lo);
            } else {
                areg[vt][ks] = 0;
            }
        }
        #pragma unroll
        for (int r = 0; r < 4; ++r) {
            int vb = v0 + vt * 16 + quad * 4 + r;
            bb[vt][r] = (vb < V) ? bias[vb] : -1e30f;
        }
    }

    for (int tt = 0; tt < 64; ++tt) {
        const i64* bp = (const i64*)(pkc + (size_t)tt * KS * 512);
        i64 b[KS];
        #pragma unroll
        for (int ks = 0; ks < KS; ++ks) b[ks] = bp[ks * 64 + lane];
        float e = 0.f;
        #pragma unroll
        for (int vt = 0; vt < VT; ++vt) {
            f32x4 acc;
            if constexpr (KS >= 8) {
                f32x4 x0 = {0,0,0,0}, x1 = {0,0,0,0};
                #pragma unroll
                for (int j = 0; j < KS / 2; ++j) {
                    x0 = __builtin_amdgcn_mfma_f32_16x16x32_fp8_fp8(areg[vt][j], b[j], x0, 0, 0, 0);
                    x1 = __builtin_amdgcn_mfma_f32_16x16x32_fp8_fp8(areg[vt][KS/2 + j], b[KS/2 + j], x1, 0, 0, 0);
                }
                acc = x0 + x1;
            } else {
                f32x4 x0 = {0,0,0,0};
                #pragma unroll
                for (int j = 0; j < KS; ++j)
                    x0 = __builtin_amdgcn_mfma_f32_16x16x32_fp8_fp8(areg[vt][j], b[j], x0, 0, 0, 0);
                acc = x0;
            }
            e += __expf(acc[0] + bb[vt][0]) + __expf(acc[1] + bb[vt][1]) +
                 __expf(acc[2] + bb[vt][2]) + __expf(acc[3] + bb[vt][3]);
        }
        e += __shfl_xor(e, 16, 64);
        e += __shfl_xor(e, 32, 64);
        if (lane < 16) atomicAdd(&bsum[tt * 16 + lane], e);
    }
    __syncthreads();
    for (int i = tid; i < NTOK; i += 256)
        atomicAdd(&sumrowc[i], bsum[i]);
}

#define NB0 157
#define NB1 79
#define NB2 625
#define NB3 265

__global__ __launch_bounds__(256) void lse_all(const float* __restrict__ w0, const float* __restrict__ b0,
                                               const float* __restrict__ w1, const float* __restrict__ b1,
                                               const float* __restrict__ w2, const float* __restrict__ b2,
                                               const float* __restrict__ w3, const float* __restrict__ b3,
                                               const unsigned char* __restrict__ pk0,
                                               const unsigned char* __restrict__ pk1,
                                               const unsigned char* __restrict__ pk2,
                                               const unsigned char* __restrict__ pk3,
                                               float* __restrict__ sums) {
    __shared__ float bsum[NTOK];
    int bid = blockIdx.x;
    if (bid < NB0) {
        lse_cluster<32, 2>(w0, b0, pk0, sums,            HEADS,  1024, bid, bsum);
    } else if (bid < NB0 + NB1) {
        lse_cluster<8, 4>(w1, b1, pk1, sums + NTOK,      20000,  256,  bid - NB0, bsum);
    } else if (bid < NB0 + NB1 + NB2) {
        lse_cluster<2, 4>(w2, b2, pk2, sums + 2 * NTOK,  160000, 64,   bid - NB0 - NB1, bsum);
    } else {
        lse_cluster<1, 4>(w3, b3, pk3, sums + 3 * NTOK,  67735,  16,   bid - NB0 - NB1 - NB2, bsum);
    }
}

// ================= finalize (exact fp32 gathered logits) ========================
__global__ __launch_bounds__(256) void finalize(const int* __restrict__ target,
                                                const float* __restrict__ projf,
                                                const float* __restrict__ sums,
                                                const float* __restrict__ w0, const float* __restrict__ b0,
                                                const float* __restrict__ w1, const float* __restrict__ b1,
                                                const float* __restrict__ w2, const float* __restrict__ b2,
                                                const float* __restrict__ w3, const float* __restrict__ b3,
                                                float* __restrict__ out) {
    int wave = threadIdx.x >> 6, lane = threadIdx.x & 63;
    int row = blockIdx.x * 4 + wave;
    int t = target[row];
    int c = (t < 20000) ? 0 : (t < 40000) ? 1 : (t < 200000) ? 2 : 3;
    int col0 = (c == 0) ? t : (HEADS - c);
    const float* pr = projf + row * PSTRIDE;

    float s = 0.f;
    for (int k = lane; k < DPROJ; k += 64) s += pr[k] * w0[col0 * DPROJ + k];
    #pragma unroll
    for (int off = 32; off; off >>= 1) s += __shfl_xor(s, off, 64);
    float hl = s + b0[col0];
    float lse0 = __logf(sums[row]);

    float res;
    if (c == 0) {
        res = lse0 - hl;
    } else {
        const float* wc; const float* bc; int d, coloff, l;
        if (c == 1)      { wc = w1; bc = b1; d = 256; coloff = 1024; l = 20000; }
        else if (c == 2) { wc = w2; bc = b2; d = 64;  coloff = 1280; l = 40000; }
        else             { wc = w3; bc = b3; d = 16;  coloff = 1344; l = 200000; }
        int tc = t - l;
        float s2 = 0.f;
        for (int k = lane; k < d; k += 64) s2 += pr[coloff + k] * wc[tc * d + k];
        #pragma unroll
        for (int off = 32; off; off >>= 1) s2 += __shfl_xor(s2, off, 64);
        float tl = s2 + bc[tc];
        float lsec = __logf(sums[c * NTOK + row]);
        res = lse0 - hl + lsec - tl;
    }
    if (lane == 0) out[row] = res;
}

// ================= workspace layout =============================================
// hbP   (short) @ 0          : 1,048,576 elems
// pTbP0 (short) @ 1,048,576  : 1,048,576
// pTbP1 (short) @ 2,097,152  :   262,144
// pTbP2 (short) @ 2,359,296  :    65,536
// pTbP3 (short) @ 2,424,832  :    16,384
// projf (float) @ byte 4,882,432 : 1,409,024 floats
// pk0..3 (u8)   @ byte 10,518,528: 1 MB / 256 KB / 64 KB / 32 KB
// sums  (float) : overlaps pTbP0 (dead after proj)

extern "C" void kernel_launch(void* const* d_in, const int* in_sizes, int n_in,
                              void* d_out, int out_size, void* d_ws, size_t ws_size,
                              hipStream_t stream) {
    const float* hidden = (const float*)d_in[0];
    const int*   target = (const int*)d_in[1];
    const float* w0 = (const float*)d_in[2];
    const float* b0 = (const float*)d_in[3];
    const float* p0 = (const float*)d_in[4];
    const float* w1 = (const float*)d_in[5];
    const float* b1 = (const float*)d_in[6];
    const float* p1 = (const float*)d_in[7];
    const float* w2 = (const float*)d_in[8];
    const float* b2 = (const float*)d_in[9];
    const float* p2 = (const float*)d_in[10];
    const float* w3 = (const float*)d_in[11];
    const float* b3 = (const float*)d_in[12];
    const float* p3 = (const float*)d_in[13];

    short* base = (short*)d_ws;
    short* hbP   = base;
    short* pTbP0 = base + 1048576;
    short* pTbP1 = base + 2097152;
    short* pTbP2 = base + 2359296;
    short* pTbP3 = base + 2424832;
    float* projf = (float*)((char*)d_ws + 4882432);
    unsigned char* pk0 = (unsigned char*)d_ws + 10518528;
    unsigned char* pk1 = pk0 + 1048576;
    unsigned char* pk2 = pk1 + 262144;
    unsigned char* pk3 = pk2 + 65536;
    float* sums  = (float*)pTbP0;          // reuse: pTbP0 dead after proj

    prep<<<416, 256, 0, stream>>>(hidden, p0, p1, p2, p3, hbP, pTbP0, pTbP1, pTbP2, pTbP3);
    hipMemsetAsync(pk3, 0, 32768, stream);          // c3 k-pad zeros
    proj<<<dim3(64, 22), 256, 0, stream>>>(hbP, pTbP0, pTbP1, pTbP2, pTbP3,
                                           projf, pk0, pk1, pk2, pk3);
    hipMemsetAsync(sums, 0, 4 * NTOK * sizeof(float), stream);   // after proj: safe overlap
    lse_all<<<NB0 + NB1 + NB2 + NB3, 256, 0, stream>>>(w0, b0, w1, b1, w2, b2, w3, b3,
                                                       pk0, pk1, pk2, pk3, sums);
    finalize<<<256, 256, 0, stream>>>(target, projf, sums,
                                      w0, b0, w1, b1, w2, b2, w3, b3, (float*)d_out);
}

// Round 6
// 350.035 us; speedup vs baseline: 1.8761x; 1.0612x over previous
//
#include <hip/hip_runtime.h>
#include <hip/hip_bf16.h>
#include <math.h>

#define NTOK 1024
#define DPROJ 1024
#define PSTRIDE 1376
#define HEADS 20003
#define LOG2E 1.4426950408889634f
#define LN2   0.6931471805599453f
#define WSCALE (4.0f * LOG2E)
#define PSCALE 0.25f

typedef __attribute__((ext_vector_type(8))) short bf16x8;
typedef __attribute__((ext_vector_type(4))) float f32x4;
typedef long long i64;

__device__ __forceinline__ short f2bf(float f) {
    unsigned u = __float_as_uint(f);
    u += 0x7fffu + ((u >> 16) & 1u);
    return (short)(u >> 16);
}
__device__ __forceinline__ unsigned pk4fp8(float a, float b, float c, float d) {
    unsigned v = __builtin_amdgcn_cvt_pk_fp8_f32(a, b, 0, false);
    v = __builtin_amdgcn_cvt_pk_fp8_f32(c, d, v, true);
    return v;
}
__device__ __forceinline__ unsigned char fp8_1(float a) {
    return (unsigned char)(__builtin_amdgcn_cvt_pk_fp8_f32(a, a, 0, false) & 0xff);
}
// w row fragment -> fp8 with WSCALE
__device__ __forceinline__ i64 wfrag(const float* wp) {
    float4 x = *(const float4*)(wp);
    float4 y = *(const float4*)(wp + 4);
    unsigned lo = pk4fp8(x.x * WSCALE, x.y * WSCALE, x.z * WSCALE, x.w * WSCALE);
    unsigned hi = pk4fp8(y.x * WSCALE, y.y * WSCALE, y.z * WSCALE, y.w * WSCALE);
    return (i64)(((unsigned long long)hi << 32) | lo);
}

// ================= prep (+ absorbed memsets) ====================================
__global__ __launch_bounds__(256) void prep(const float* __restrict__ hidden,
                                            const float* __restrict__ p0,
                                            const float* __restrict__ p1,
                                            const float* __restrict__ p2,
                                            const float* __restrict__ p3,
                                            short* __restrict__ hbP,
                                            short* __restrict__ pTbP0,
                                            short* __restrict__ pTbP1,
                                            short* __restrict__ pTbP2,
                                            short* __restrict__ pTbP3,
                                            float* __restrict__ sums,
                                            unsigned char* __restrict__ pk3) {
    __shared__ float tile[64][65];
    int bid = blockIdx.x, tid = threadIdx.x;
    if (bid == 416) {                       // zero sums (4*1024 floats)
        float4 z = {0.f, 0.f, 0.f, 0.f};
        #pragma unroll
        for (int i = 0; i < 4; ++i) *((float4*)sums + i * 256 + tid) = z;
        return;
    }
    if (bid == 417) {                       // zero pk3 (32768 B, for k-pad)
        int4 z = {0, 0, 0, 0};
        #pragma unroll
        for (int i = 0; i < 8; ++i) *((int4*)pk3 + i * 256 + tid) = z;
        return;
    }
    if (bid < 64) {
        int tt = bid;
        #pragma unroll
        for (int q = 0; q < 8; ++q) {
            int fi = q * 256 + tid;
            int l = fi & 63;
            int row = tt * 16 + (l & 15);
            int kb = (fi >> 6) * 32 + (l >> 4) * 8;
            const float* hp = hidden + row * 1024 + kb;
            float4 x = *(const float4*)hp;
            float4 y = *(const float4*)(hp + 4);
            bf16x8 o;
            o[0]=f2bf(x.x); o[1]=f2bf(x.y); o[2]=f2bf(x.z); o[3]=f2bf(x.w);
            o[4]=f2bf(y.x); o[5]=f2bf(y.y); o[6]=f2bf(y.z); o[7]=f2bf(y.w);
            *(bf16x8*)(hbP + (size_t)tt * 16384 + fi * 8) = o;
        }
        return;
    }
    int lb = bid - 64;
    const float* p; short* dst; int d, kt, jb;
    if (lb < 256)      { p = p0; dst = pTbP0; d = 1024; kt = lb >> 4; jb = lb & 15; }
    else if (lb < 320) { lb -= 256; p = p1; dst = pTbP1; d = 256; kt = lb >> 2; jb = lb & 3; }
    else if (lb < 336) { lb -= 320; p = p2; dst = pTbP2; d = 64;  kt = lb; jb = 0; }
    else               { lb -= 336; p = p3; dst = pTbP3; d = 16;  kt = lb; jb = 0; }
    int k0 = kt * 64, j0 = jb * 64;
    int tx = tid & 63, ty = tid >> 6;
    #pragma unroll
    for (int rr = 0; rr < 16; ++rr) {
        int k = k0 + ty * 16 + rr;
        int j = j0 + tx;
        if (j < d) tile[ty * 16 + rr][tx] = p[k * d + j];
    }
    __syncthreads();
    int ch = tid >> 5;
    int jtl = ch >> 1, ksl = ch & 1;
    int jt = jb * 4 + jtl;
    if (jt * 16 < d) {
        #pragma unroll
        for (int li = 0; li < 2; ++li) {
            int l = (tid & 31) + li * 32;
            int jl = jtl * 16 + (l & 15);
            int kl = ksl * 32 + (l >> 4) * 8;
            bf16x8 o;
            #pragma unroll
            for (int e = 0; e < 8; ++e) o[e] = f2bf(tile[kl + e][jl]);
            *(bf16x8*)(dst + ((size_t)jt * 32 + kt * 2 + ksl) * 512 + l * 8) = o;
        }
    }
}

// ================= proj: bf16 MFMA; projf fp32 exact; pk fp8 scaled =============
__global__ __launch_bounds__(256) void proj(const short* __restrict__ hbP,
                                            const short* __restrict__ pTbP0,
                                            const short* __restrict__ pTbP1,
                                            const short* __restrict__ pTbP2,
                                            const short* __restrict__ pTbP3,
                                            float* __restrict__ projf,
                                            unsigned char* __restrict__ pk0,
                                            unsigned char* __restrict__ pk1,
                                            unsigned char* __restrict__ pk2,
                                            unsigned char* __restrict__ pk3) {
    __shared__ float spackf[16][72];
    __shared__ unsigned char sp8[1024];
    int tt = blockIdx.x, jbG = blockIdx.y, tid = threadIdx.x;
    const short* pB; unsigned char* pkc; int d, KSp, coloff, jb;
    if (jbG < 16)      { pB = pTbP0; pkc = pk0; d = 1024; KSp = 32; coloff = 0;    jb = jbG; }
    else if (jbG < 20) { pB = pTbP1; pkc = pk1; d = 256;  KSp = 8;  coloff = 1024; jb = jbG - 16; }
    else if (jbG == 20){ pB = pTbP2; pkc = pk2; d = 64;   KSp = 2;  coloff = 1280; jb = 0; }
    else               { pB = pTbP3; pkc = pk3; d = 16;   KSp = 1;  coloff = 1344; jb = 0; }
    int w = tid >> 6, lane = tid & 63;
    int l16 = lane & 15, quad = lane >> 4;
    int jt = jb * 4 + w;
    if (jt * 16 < d) {
        const short* ap = hbP + ((size_t)tt * 32) * 512 + lane * 8;
        const short* bp = pB  + ((size_t)jt * 32) * 512 + lane * 8;
        f32x4 x0 = {0,0,0,0}, x1 = {0,0,0,0};
        #pragma unroll
        for (int ks = 0; ks < 16; ++ks) {
            bf16x8 a0 = *(const bf16x8*)(ap + ks * 512);
            bf16x8 b0 = *(const bf16x8*)(bp + ks * 512);
            bf16x8 a1 = *(const bf16x8*)(ap + (ks + 16) * 512);
            bf16x8 b1 = *(const bf16x8*)(bp + (ks + 16) * 512);
            x0 = __builtin_amdgcn_mfma_f32_16x16x32_bf16(a0, b0, x0, 0, 0, 0);
            x1 = __builtin_amdgcn_mfma_f32_16x16x32_bf16(a1, b1, x1, 0, 0, 0);
        }
        f32x4 acc = x0 + x1;
        int kk = w * 16 + l16;
        #pragma unroll
        for (int r = 0; r < 4; ++r) {
            int tok = quad * 4 + r;
            spackf[tok][kk] = acc[r];
            sp8[(kk >> 5) * 512 + ((kk & 31) >> 3) * 128 + tok * 8 + (kk & 7)] = fp8_1(acc[r] * PSCALE);
        }
    }
    __syncthreads();
    int j0g = jb * 64;
    int dcols = min(64, d - j0g);
    {
        int row = tid >> 4, cb = (tid & 15) * 4;
        if (cb < dcols) {
            float4 v = *(const float4*)&spackf[row][cb];
            *(float4*)&projf[(tt * 16 + row) * PSTRIDE + coloff + j0g + cb] = v;
        }
    }
    {
        int nbytes = 16 * dcols;
        if (tid * 4 < nbytes) {
            unsigned char* gdst = pkc + ((size_t)tt * KSp + (j0g >> 5)) * 512;
            *(unsigned*)(gdst + tid * 4) = *(const unsigned*)(sp8 + tid * 4);
        }
    }
}

// ================= lse =========================================================
__device__ __forceinline__ void stage16k(const unsigned char* g, unsigned char* l,
                                         int wave, int lane) {
    const unsigned char* gs = g + wave * 4096 + lane * 16;
    unsigned char* ls = l + wave * 4096;
    #pragma unroll
    for (int i = 0; i < 4; ++i)
        __builtin_amdgcn_global_load_lds(
            (const __attribute__((address_space(1))) unsigned*)(gs + i * 1024),
            (__attribute__((address_space(3))) unsigned*)(ls + i * 1024), 16, 0, 0);
}

// head: VT=2, KS=32, LDS double-buffered B (m97 pattern)
__device__ __forceinline__ void lse_head(const float* __restrict__ w,
                                         const float* __restrict__ bias,
                                         const unsigned char* __restrict__ pk,
                                         float* __restrict__ sumrow, int bid,
                                         unsigned char (*sbuf)[16384], float* bsum) {
    int tid = threadIdx.x;
    int wave = tid >> 6, lane = tid & 63;
    int quad = lane >> 4, l16 = lane & 15;
    int v0 = bid * 128 + wave * 32;

    for (int i = tid; i < NTOK; i += 256) bsum[i] = 0.f;

    i64 areg[2][32];
    float bb[2][4];
    #pragma unroll
    for (int vt = 0; vt < 2; ++vt) {
        int va = v0 + vt * 16 + l16;
        #pragma unroll
        for (int ks = 0; ks < 32; ++ks) {
            areg[vt][ks] = (va < HEADS) ? wfrag(w + (long)va * 1024 + ks * 32 + quad * 8) : 0;
        }
        #pragma unroll
        for (int r = 0; r < 4; ++r) {
            int vb = v0 + vt * 16 + quad * 4 + r;
            bb[vt][r] = (vb < HEADS) ? bias[vb] * LOG2E : -1e30f;
        }
    }

    stage16k(pk, sbuf[0], wave, lane);
    __syncthreads();
    for (int tt = 0; tt < 64; ++tt) {
        if (tt < 63) stage16k(pk + (size_t)(tt + 1) * 16384, sbuf[(tt + 1) & 1], wave, lane);
        const unsigned char* sb = sbuf[tt & 1];
        f32x4 x0 = {0,0,0,0}, x1 = x0, x2 = x0, x3 = x0;
        #pragma unroll
        for (int j = 0; j < 16; ++j) {
            i64 b0 = *(const i64*)(sb + j * 512 + lane * 8);
            i64 b1 = *(const i64*)(sb + (j + 16) * 512 + lane * 8);
            x0 = __builtin_amdgcn_mfma_f32_16x16x32_fp8_fp8(areg[0][j],      b0, x0, 0, 0, 0);
            x1 = __builtin_amdgcn_mfma_f32_16x16x32_fp8_fp8(areg[0][j + 16], b1, x1, 0, 0, 0);
            x2 = __builtin_amdgcn_mfma_f32_16x16x32_fp8_fp8(areg[1][j],      b0, x2, 0, 0, 0);
            x3 = __builtin_amdgcn_mfma_f32_16x16x32_fp8_fp8(areg[1][j + 16], b1, x3, 0, 0, 0);
        }
        f32x4 a0 = x0 + x1, a1 = x2 + x3;
        float e0 = exp2f(a0[0] + bb[0][0]) + exp2f(a0[2] + bb[0][2]) +
                   exp2f(a1[0] + bb[1][0]) + exp2f(a1[2] + bb[1][2]);
        float e1 = exp2f(a0[1] + bb[0][1]) + exp2f(a0[3] + bb[0][3]) +
                   exp2f(a1[1] + bb[1][1]) + exp2f(a1[3] + bb[1][3]);
        float e = e0 + e1;
        e += __shfl_xor(e, 16, 64);
        e += __shfl_xor(e, 32, 64);
        if (lane < 16) atomicAdd(&bsum[tt * 16 + lane], e);
        __syncthreads();
    }
    for (int i = tid; i < NTOK; i += 256)
        atomicAdd(&sumrow[i], bsum[i]);
}

// tails: global-direct B with register double-buffer
template <int KS, int VT>
__device__ __forceinline__ void lse_tail(const float* __restrict__ w,
                                         const float* __restrict__ bias,
                                         const unsigned char* __restrict__ pk,
                                         float* __restrict__ sumrow,
                                         int V, int D, int bid, float* bsum) {
    int tid = threadIdx.x;
    int wave = tid >> 6, lane = tid & 63;
    int quad = lane >> 4, l16 = lane & 15;
    int v0 = bid * (64 * VT) + wave * (16 * VT);

    for (int i = tid; i < NTOK; i += 256) bsum[i] = 0.f;
    __syncthreads();

    i64 areg[VT][KS];
    float bb[VT][4];
    #pragma unroll
    for (int vt = 0; vt < VT; ++vt) {
        int va = v0 + vt * 16 + l16;
        #pragma unroll
        for (int ks = 0; ks < KS; ++ks) {
            int k = ks * 32 + quad * 8;
            areg[vt][ks] = (va < V && k < D) ? wfrag(w + (long)va * D + k) : 0;
        }
        #pragma unroll
        for (int r = 0; r < 4; ++r) {
            int vb = v0 + vt * 16 + quad * 4 + r;
            bb[vt][r] = (vb < V) ? bias[vb] * LOG2E : -1e30f;
        }
    }

    const i64* base = (const i64*)pk;
    i64 bn[KS];
    #pragma unroll
    for (int k = 0; k < KS; ++k) bn[k] = base[k * 64 + lane];
    for (int tt = 0; tt < 64; ++tt) {
        i64 bc[KS];
        #pragma unroll
        for (int k = 0; k < KS; ++k) bc[k] = bn[k];
        if (tt < 63) {
            const i64* nb = base + (size_t)(tt + 1) * KS * 64;
            #pragma unroll
            for (int k = 0; k < KS; ++k) bn[k] = nb[k * 64 + lane];
        }
        float e0 = 0.f, e1 = 0.f;
        #pragma unroll
        for (int vt = 0; vt < VT; ++vt) {
            f32x4 acc;
            if constexpr (KS >= 2) {
                f32x4 y0 = {0,0,0,0}, y1 = {0,0,0,0};
                #pragma unroll
                for (int j = 0; j < KS / 2; ++j) {
                    y0 = __builtin_amdgcn_mfma_f32_16x16x32_fp8_fp8(areg[vt][j], bc[j], y0, 0, 0, 0);
                    y1 = __builtin_amdgcn_mfma_f32_16x16x32_fp8_fp8(areg[vt][KS/2 + j], bc[KS/2 + j], y1, 0, 0, 0);
                }
                acc = y0 + y1;
            } else {
                f32x4 y0 = {0,0,0,0};
                acc = __builtin_amdgcn_mfma_f32_16x16x32_fp8_fp8(areg[vt][0], bc[0], y0, 0, 0, 0);
            }
            e0 += exp2f(acc[0] + bb[vt][0]) + exp2f(acc[2] + bb[vt][2]);
            e1 += exp2f(acc[1] + bb[vt][1]) + exp2f(acc[3] + bb[vt][3]);
        }
        float e = e0 + e1;
        e += __shfl_xor(e, 16, 64);
        e += __shfl_xor(e, 32, 64);
        if (lane < 16) atomicAdd(&bsum[tt * 16 + lane], e);
    }
    __syncthreads();
    for (int i = tid; i < NTOK; i += 256)
        atomicAdd(&sumrow[i], bsum[i]);
}

#define NB0 157
#define NB1 79
#define NB2 625
#define NB3 265

__global__ __launch_bounds__(256, 2) void lse_all(const float* __restrict__ w0, const float* __restrict__ b0,
                                                  const float* __restrict__ w1, const float* __restrict__ b1,
                                                  const float* __restrict__ w2, const float* __restrict__ b2,
                                                  const float* __restrict__ w3, const float* __restrict__ b3,
                                                  const unsigned char* __restrict__ pk0,
                                                  const unsigned char* __restrict__ pk1,
                                                  const unsigned char* __restrict__ pk2,
                                                  const unsigned char* __restrict__ pk3,
                                                  float* __restrict__ sums) {
    __shared__ unsigned char sbuf[2][16384];
    __shared__ float bsum[NTOK];
    int bid = blockIdx.x;
    if (bid < NB0) {
        lse_head(w0, b0, pk0, sums, bid, sbuf, bsum);
    } else if (bid < NB0 + NB1) {
        lse_tail<8, 4>(w1, b1, pk1, sums + NTOK,     20000,  256, bid - NB0, bsum);
    } else if (bid < NB0 + NB1 + NB2) {
        lse_tail<2, 4>(w2, b2, pk2, sums + 2 * NTOK, 160000, 64,  bid - NB0 - NB1, bsum);
    } else {
        lse_tail<1, 4>(w3, b3, pk3, sums + 3 * NTOK, 67735,  16,  bid - NB0 - NB1 - NB2, bsum);
    }
}

// ================= finalize ====================================================
__global__ __launch_bounds__(256) void finalize(const int* __restrict__ target,
                                                const float* __restrict__ projf,
                                                const float* __restrict__ sums,
                                                const float* __restrict__ w0, const float* __restrict__ b0,
                                                const float* __restrict__ w1, const float* __restrict__ b1,
                                                const float* __restrict__ w2, const float* __restrict__ b2,
                                                const float* __restrict__ w3, const float* __restrict__ b3,
                                                float* __restrict__ out) {
    int wave = threadIdx.x >> 6, lane = threadIdx.x & 63;
    int row = blockIdx.x * 4 + wave;
    int t = target[row];
    int c = (t < 20000) ? 0 : (t < 40000) ? 1 : (t < 200000) ? 2 : 3;
    int col0 = (c == 0) ? t : (HEADS - c);
    const float* pr = projf + row * PSTRIDE;

    float s = 0.f;
    for (int k = lane; k < DPROJ; k += 64) s += pr[k] * w0[col0 * DPROJ + k];
    #pragma unroll
    for (int off = 32; off; off >>= 1) s += __shfl_xor(s, off, 64);
    float hl = s + b0[col0];
    float lse0 = __log2f(sums[row]) * LN2;

    float res;
    if (c == 0) {
        res = lse0 - hl;
    } else {
        const float* wc; const float* bc; int d, coloff, l;
        if (c == 1)      { wc = w1; bc = b1; d = 256; coloff = 1024; l = 20000; }
        else if (c == 2) { wc = w2; bc = b2; d = 64;  coloff = 1280; l = 40000; }
        else             { wc = w3; bc = b3; d = 16;  coloff = 1344; l = 200000; }
        int tc = t - l;
        float s2 = 0.f;
        for (int k = lane; k < d; k += 64) s2 += pr[coloff + k] * wc[tc * d + k];
        #pragma unroll
        for (int off = 32; off; off >>= 1) s2 += __shfl_xor(s2, off, 64);
        float tl = s2 + bc[tc];
        float lsec = __log2f(sums[c * NTOK + row]) * LN2;
        res = lse0 - hl + lsec - tl;
    }
    if (lane == 0) out[row] = res;
}

// ================= workspace layout =============================================
// hbP   (short) @ elem 0          : 1,048,576
// pTbP0 (short) @ elem 1,048,576  : 1,048,576
// pTbP1 (short) @ elem 2,097,152  :   262,144
// pTbP2 (short) @ elem 2,359,296  :    65,536
// pTbP3 (short) @ elem 2,424,832  :    16,384
// projf (float) @ byte 4,882,432  : 1,409,024 floats
// pk0..3 (u8)   @ byte 10,518,528 : 1 MB / 256 KB / 64 KB / 32 KB
// sums  (float) @ byte 11,927,552 : 4096 floats

extern "C" void kernel_launch(void* const* d_in, const int* in_sizes, int n_in,
                              void* d_out, int out_size, void* d_ws, size_t ws_size,
                              hipStream_t stream) {
    const float* hidden = (const float*)d_in[0];
    const int*   target = (const int*)d_in[1];
    const float* w0 = (const float*)d_in[2];
    const float* b0 = (const float*)d_in[3];
    const float* p0 = (const float*)d_in[4];
    const float* w1 = (const float*)d_in[5];
    const float* b1 = (const float*)d_in[6];
    const float* p1 = (const float*)d_in[7];
    const float* w2 = (const float*)d_in[8];
    const float* b2 = (const float*)d_in[9];
    const float* p2 = (const float*)d_in[10];
    const float* w3 = (const float*)d_in[11];
    const float* b3 = (const float*)d_in[12];
    const float* p3 = (const float*)d_in[13];

    short* base = (short*)d_ws;
    short* hbP   = base;
    short* pTbP0 = base + 1048576;
    short* pTbP1 = base + 2097152;
    short* pTbP2 = base + 2359296;
    short* pTbP3 = base + 2424832;
    float* projf = (float*)((char*)d_ws + 4882432);
    unsigned char* pk0 = (unsigned char*)d_ws + 10518528;
    unsigned char* pk1 = pk0 + 1048576;
    unsigned char* pk2 = pk1 + 262144;
    unsigned char* pk3 = pk2 + 65536;
    float* sums  = (float*)((char*)d_ws + 11927552);

    prep<<<418, 256, 0, stream>>>(hidden, p0, p1, p2, p3,
                                  hbP, pTbP0, pTbP1, pTbP2, pTbP3, sums, pk3);
    proj<<<dim3(64, 22), 256, 0, stream>>>(hbP, pTbP0, pTbP1, pTbP2, pTbP3,
                                           projf, pk0, pk1, pk2, pk3);
    lse_all<<<NB0 + NB1 + NB2 + NB3, 256, 0, stream>>>(w0, b0, w1, b1, w2, b2, w3, b3,
                                                       pk0, pk1, pk2, pk3, sums);
    finalize<<<256, 256, 0, stream>>>(target, projf, sums,
                                      w0, b0, w1, b1, w2, b2, w3, b3, (float*)d_out);
}